// Round 14
// baseline (155.073 us; speedup 1.0000x reference)
//
#include <hip/hip_runtime.h>
#include <hip/hip_bf16.h>
#include <math.h>

// Cart2Polar: output[b,c,y,x] = bilinear_sample(grid_feat[b,c], gx(y,x), gy(y,x))
// ref_feat is fully overwritten by the reference's scatter -> unused.
// Shapes (fixed): grid_feat [4,64,480,480] f32, out [4,64,480,360] f32.
//
// R14 = R13 minus the nontemporal store hint. R13's WRITE_SIZE was 230MB vs
// 172.8 ideal: nt-stores stream 64B half-lines straight out of L2, so the
// two adjacent xt-tiles' halves of each 128B output line never write-combine.
// Plain stores linger in L2 (same-XCD, temporally adjacent blocks write the
// other half) -> full-line writebacks. Everything else identical to R13
// (bench 118.9: 16y x 4x wave gather, paired dwordx2 asm cluster, counted
// vmcnt drain, LDS-transposed 64B-row stores, CSPLIT=8 TLP).

#define BB 4
#define CC 64
#define HC 480
#define WC 480
#define HP 480
#define WP 360

#define TY 16
#define TX 16
#define BYT (HP / TY)                  // 30
#define BXT ((WP + TX - 1) / TX)       // 23 (last tile x>=360 lanes: computed, not stored)
#define CSPLIT 8
#define CCB (CC / CSPLIT)              // 8 channels per block
#define NWG (BB * BYT * BXT * CSPLIT)  // 22080
#define CB 8                           // = CCB, single LDS batch

typedef float f2a __attribute__((ext_vector_type(2), aligned(8)));

__global__ __launch_bounds__(256, 2) void c2p_kernel(const float* __restrict__ g,
                                                     float* __restrict__ out) {
    __shared__ float lds[CB][TY][TX + 1];   // +1 pad: conflict-free scalar r/w

    // identity mapping: round-robin over XCDs mixes radii (load balance, R8 win)
    const int logical = blockIdx.x;
    const int h  = logical & (CSPLIT - 1);
    const int t1 = logical >> 3;
    const int xt = t1 % BXT;
    const int t2 = t1 / BXT;
    const int yt = t2 % BYT;
    const int b  = t2 / BYT;

    const int tid  = threadIdx.x;
    const int lane = tid & 63;
    const int w    = tid >> 6;
    // gather-phase mapping: wave = 16 consecutive y (radii) x 4 consecutive x
    const int ly = lane >> 2;                 // 0..15
    const int lx = (w << 2) | (lane & 3);     // 0..15
    const int y  = yt * TY + ly;
    const int x  = xt * TX + lx;              // may be >=360 in last tile (not stored)

    // polar grid math (matches reference, fp32)
    const float PI = 3.14159265358979323846f;
    float theta = PI - (float)x * (2.0f * PI / (float)WP);
    float r = ((float)HP - 0.5f - (float)y + 3.0f) * (1.0f / ((float)HP + 3.0f)) * ((float)WC * 0.5f);
    float s, c;
    __sincosf(theta, &s, &c);
    float index_x = r * c + (float)WC * 0.5f;
    float index_y = r * s + (float)WC * 0.5f;
    const float scale = (float)(WC - 1) / (float)WC;
    float gx = index_x * scale;
    float gy = index_y * scale;

    float x0f = floorf(gx);
    float y0f = floorf(gy);
    float wx1 = gx - x0f;
    float wy1 = gy - y0f;
    float wx0 = 1.0f - wx1;
    float wy0 = 1.0f - wy1;

    // proven in-bounds for this geometry: x0,y0 in [0,478] -> no clamp/validity
    const int x0 = (int)x0f;
    const int y0 = (int)y0f;

    const float w00 = wx0 * wy0;
    const float w10 = wx1 * wy0;
    const float w01 = wx0 * wy1;
    const float w11 = wx1 * wy1;

    const int o0 = y0 * WC + x0;     // row y0, cols (x0, x0+1) as one float2
    const int o1 = o0 + WC;          // row y0+1

    constexpr int HWc = HC * WC;
    constexpr int HWp = HP * WP;

    const float* __restrict__ base = g + ((size_t)b * CC + h * CCB) * HWc;

    // store-phase mapping: x-major, 16 rows x 64B per wave-store
    const int srow = tid >> 4;                // 0..15
    const int scol = tid & 15;                // 0..15
    const int sy = yt * TY + srow;
    const int sx = xt * TX + scol;
    const bool sok = (sx < WP);
    float* __restrict__ ob = out + ((size_t)b * CC + h * CCB) * HWp + (size_t)sy * WP + sx;

    // ---- asm-forced gather cluster: 16 dwordx2 loads, all in flight ----
    f2a a0[CB], a1[CB];
#pragma unroll
    for (int j = 0; j < CB; ++j) {
        const float* p0 = base + (size_t)j * HWc + o0;
        const float* p1 = base + (size_t)j * HWc + o1;
        asm volatile("global_load_dwordx2 %0, %1, off"
                     : "=v"(a0[j]) : "v"(p0));
        asm volatile("global_load_dwordx2 %0, %1, off"
                     : "=v"(a1[j]) : "v"(p1));
    }

    // ---- counted drain: consume channel j while 2*(CB-1-j) loads still fly ----
#pragma unroll
    for (int j = 0; j < CB; ++j) {
        asm volatile("s_waitcnt vmcnt(%0)" :: "i"(2 * (CB - 1 - j)) : "memory");
        __builtin_amdgcn_sched_barrier(0);
        lds[j][ly][lx] = a0[j].x * w00 + a0[j].y * w10
                       + a1[j].x * w01 + a1[j].y * w11;
    }
    __syncthreads();

    if (sok) {
        // plain stores: L2 write-combines the 64B halves into full lines
#pragma unroll
        for (int j = 0; j < CB; ++j)
            ob[(size_t)j * HWp] = lds[j][srow][scol];
    }
}

extern "C" void kernel_launch(void* const* d_in, const int* in_sizes, int n_in,
                              void* d_out, int out_size, void* d_ws, size_t ws_size,
                              hipStream_t stream) {
    const float* grid_feat = (const float*)d_in[0];
    float* out = (float*)d_out;
    c2p_kernel<<<NWG, 256, 0, stream>>>(grid_feat, out);
}

// Round 15
// 124.889 us; speedup vs baseline: 1.2417x; 1.2417x over previous
//
#include <hip/hip_runtime.h>
#include <hip/hip_bf16.h>
#include <math.h>

// Cart2Polar: output[b,c,y,x] = bilinear_sample(grid_feat[b,c], gx(y,x), gy(y,x))
// ref_feat is fully overwritten by the reference's scatter -> unused.
// Shapes (fixed): grid_feat [4,64,480,480] f32, out [4,64,480,360] f32.
//
// R15 = R13 (best bench 118.9) + full-line nt stores.
// R13/R14 A/B proved: nt stores win at bench time (L2 stays clean for the
// gather working set; plain stores regressed 119->155), but R13's 64B
// half-line nt stores wasted write BW (WRITE 230 vs 172.8 MB ideal).
// Fix: 16y x 32x output tile stored as full 128B lines, gathered as two
// sequential 16-col halves with the UNCHANGED 16y x 4x wave footprint
// (the proven-best gather geometry). Half B's theta = half A's - 16*dtheta
// via constant rotation (no second sincos). Tail tile masks stores.

#define BB 4
#define CC 64
#define HC 480
#define WC 480
#define HP 480
#define WP 360

#define TY 16
#define TX 32
#define BYT (HP / TY)                  // 30
#define BXT ((WP + TX - 1) / TX)       // 12 (xt=11 half-valid: computed, masked store)
#define CSPLIT 8
#define CCB (CC / CSPLIT)              // 8 channels per block
#define NWG (BB * BYT * BXT * CSPLIT)  // 11520
#define CB 8                           // = CCB, single LDS batch

typedef float f2a __attribute__((ext_vector_type(2), aligned(8)));

__global__ __launch_bounds__(256, 2) void c2p_kernel(const float* __restrict__ g,
                                                     float* __restrict__ out) {
    __shared__ float lds[CB][TY][TX + 1];   // [8][16][33]: 2-way max on r/w (free)

    // identity mapping: round-robin over XCDs mixes radii (load balance, R8 win)
    const int logical = blockIdx.x;
    const int h  = logical & (CSPLIT - 1);
    const int t1 = logical >> 3;
    const int xt = t1 % BXT;
    const int t2 = t1 / BXT;
    const int yt = t2 % BYT;
    const int b  = t2 / BYT;

    const int tid  = threadIdx.x;
    const int lane = tid & 63;
    const int w    = tid >> 6;
    // gather mapping (both halves): wave = 16 consecutive y x 4 consecutive x
    const int ly  = lane >> 2;                // 0..15
    const int lxA = (w << 2) | (lane & 3);    // 0..15 (half A); half B = +16
    const int y   = yt * TY + ly;
    const int xA  = xt * TX + lxA;            // may exceed 359 in tail tile:
                                              // theta wraps, sample stays in
                                              // the disk -> in-bounds reads

    // polar grid math (matches reference, fp32)
    const float PI = 3.14159265358979323846f;
    float theta = PI - (float)xA * (2.0f * PI / (float)WP);
    float r = ((float)HP - 0.5f - (float)y + 3.0f) * (1.0f / ((float)HP + 3.0f)) * ((float)WC * 0.5f);
    float sn, cs;
    __sincosf(theta, &sn, &cs);
    // half B: theta_B = theta - 16*2pi/360; rotate (cs,sn) by constant angle
    const float cd = 0.96126169593831886f;    // cos(16*2pi/360)
    const float sd = 0.27563735581699916f;    // sin(16*2pi/360)
    const float csB = cs * cd + sn * sd;
    const float snB = sn * cd - cs * sd;

    const float scale = (float)(WC - 1) / (float)WC;
    const float half = (float)WC * 0.5f;

    constexpr int HWc = HC * WC;
    constexpr int HWp = HP * WP;
    const float* __restrict__ base = g + ((size_t)b * CC + h * CCB) * HWc;

    // per-half bilinear setup
    float gxA = (r * cs + half) * scale;
    float gyA = (r * sn + half) * scale;
    float gxB = (r * csB + half) * scale;
    float gyB = (r * snB + half) * scale;

    float x0fA = floorf(gxA), y0fA = floorf(gyA);
    float x0fB = floorf(gxB), y0fB = floorf(gyB);
    const float wx1A = gxA - x0fA, wy1A = gyA - y0fA;
    const float wx1B = gxB - x0fB, wy1B = gyB - y0fB;
    const float wx0A = 1.0f - wx1A, wy0A = 1.0f - wy1A;
    const float wx0B = 1.0f - wx1B, wy0B = 1.0f - wy1B;

    const float w00A = wx0A * wy0A, w10A = wx1A * wy0A;
    const float w01A = wx0A * wy1A, w11A = wx1A * wy1A;
    const float w00B = wx0B * wy0B, w10B = wx1B * wy0B;
    const float w01B = wx0B * wy1B, w11B = wx1B * wy1B;

    const int o0A = (int)y0fA * WC + (int)x0fA;   // in-bounds (proven geometry)
    const int o1A = o0A + WC;
    const int o0B = (int)y0fB * WC + (int)x0fB;
    const int o1B = o0B + WC;

    f2a a0[CB], a1[CB];

    // ---- half A: asm gather cluster + counted drain -> lds cols 0..15 ----
#pragma unroll
    for (int j = 0; j < CB; ++j) {
        const float* p0 = base + (size_t)j * HWc + o0A;
        const float* p1 = base + (size_t)j * HWc + o1A;
        asm volatile("global_load_dwordx2 %0, %1, off" : "=v"(a0[j]) : "v"(p0));
        asm volatile("global_load_dwordx2 %0, %1, off" : "=v"(a1[j]) : "v"(p1));
    }
#pragma unroll
    for (int j = 0; j < CB; ++j) {
        asm volatile("s_waitcnt vmcnt(%0)" :: "i"(2 * (CB - 1 - j)) : "memory");
        __builtin_amdgcn_sched_barrier(0);
        lds[j][ly][lxA] = a0[j].x * w00A + a0[j].y * w10A
                        + a1[j].x * w01A + a1[j].y * w11A;
    }

    // ---- half B: same, into lds cols 16..31 ----
#pragma unroll
    for (int j = 0; j < CB; ++j) {
        const float* p0 = base + (size_t)j * HWc + o0B;
        const float* p1 = base + (size_t)j * HWc + o1B;
        asm volatile("global_load_dwordx2 %0, %1, off" : "=v"(a0[j]) : "v"(p0));
        asm volatile("global_load_dwordx2 %0, %1, off" : "=v"(a1[j]) : "v"(p1));
    }
#pragma unroll
    for (int j = 0; j < CB; ++j) {
        asm volatile("s_waitcnt vmcnt(%0)" :: "i"(2 * (CB - 1 - j)) : "memory");
        __builtin_amdgcn_sched_barrier(0);
        lds[j][ly][lxA + 16] = a0[j].x * w00B + a0[j].y * w10B
                             + a1[j].x * w01B + a1[j].y * w11B;
    }
    __syncthreads();

    // ---- store phase: 2 rows x 32 cols per wave-instr = full 128B lines ----
    const int srow = tid >> 5;                // 0..7 (also srow+8)
    const int scol = tid & 31;                // 0..31
    const int sx = xt * TX + scol;
    const bool sok = (sx < WP);
    float* __restrict__ ob = out + ((size_t)b * CC + h * CCB) * HWp
                                 + (size_t)(yt * TY + srow) * WP + sx;
    if (sok) {
#pragma unroll
        for (int j = 0; j < CB; ++j) {
            __builtin_nontemporal_store(lds[j][srow][scol],     &ob[(size_t)j * HWp]);
            __builtin_nontemporal_store(lds[j][srow + 8][scol], &ob[(size_t)j * HWp + 8 * WP]);
        }
    }
}

extern "C" void kernel_launch(void* const* d_in, const int* in_sizes, int n_in,
                              void* d_out, int out_size, void* d_ws, size_t ws_size,
                              hipStream_t stream) {
    const float* grid_feat = (const float*)d_in[0];
    float* out = (float*)d_out;
    c2p_kernel<<<NWG, 256, 0, stream>>>(grid_feat, out);
}